// Round 3
// baseline (195.164 us; speedup 1.0000x reference)
//
#include <hip/hip_runtime.h>
#include <math.h>

#define DEV __device__ __forceinline__

// Soft gate: c0 + ca*a + cb*b + cab*(a*b)
DEV float gev(float4 c, float a, float b) {
    return fmaf(c.w, a * b, fmaf(c.z, b, fmaf(c.y, a, c.x)));
}

DEV float sel4(const float h[4], int i) {
    float r = h[0];
    r = (i == 1) ? h[1] : r;
    r = (i == 2) ? h[2] : r;
    r = (i == 3) ? h[3] : r;
    return r;
}

DEV float sel2(const float h[2], int i) { return (i == 1) ? h[1] : h[0]; }

// ---------------------------------------------------------------------------
// setup_kernel: blocks [0,146) compute per-gate affine coefficients
// (softmax over 16 ops -> {c0,ca,cb,cab}); blocks [146,538) binarize +
// transpose x[100][784] -> xb[784][128] (batch-major, b fastest).
// Gate segments (cumulative float4 offsets): c1L0 0(64) c1L1 64(32)
// c1L2 96(16) c2L0 112(192) c2L1 304(96) c2L2 400(48) c3L0 448(576)
// c3L1 1024(288) c3L2 1312(144) fc1 1456(20480) fc2 21936(10240)
// fc3 32176(5120).  Total 37296.
// ---------------------------------------------------------------------------
__global__ __launch_bounds__(256) void setup_kernel(
    const float* __restrict__ w0, const float* __restrict__ w1,
    const float* __restrict__ w2, const float* __restrict__ w3,
    const float* __restrict__ w4, const float* __restrict__ w5,
    const float* __restrict__ w6, const float* __restrict__ w7,
    const float* __restrict__ w8, const float* __restrict__ w9,
    const float* __restrict__ w10, const float* __restrict__ w11,
    const float* __restrict__ x,
    float4* __restrict__ coef, float* __restrict__ xb)
{
    if (blockIdx.x >= 146) {
        int t = (blockIdx.x - 146) * 256 + threadIdx.x;   // < 784*128
        int b = t & 127, pix = t >> 7;
        float v = 0.f;
        if (b < 100) v = x[b * 784 + pix];
        xb[pix * 128 + b] = v > 0.5f ? 1.f : 0.f;
        return;
    }
    int t = blockIdx.x * 256 + threadIdx.x;
    if (t >= 37296) return;
    const float* wrow;
    if      (t < 64)    wrow = w0  + t * 16;
    else if (t < 96)    wrow = w1  + (t - 64) * 16;
    else if (t < 112)   wrow = w2  + (t - 96) * 16;
    else if (t < 304)   wrow = w3  + (t - 112) * 16;
    else if (t < 400)   wrow = w4  + (t - 304) * 16;
    else if (t < 448)   wrow = w5  + (t - 400) * 16;
    else if (t < 1024)  wrow = w6  + (t - 448) * 16;
    else if (t < 1312)  wrow = w7  + (t - 1024) * 16;
    else if (t < 1456)  wrow = w8  + (t - 1312) * 16;
    else if (t < 21936) wrow = w9  + (t - 1456) * 16;
    else if (t < 32176) wrow = w10 + (t - 21936) * 16;
    else                wrow = w11 + (t - 32176) * 16;

    const float4* wv = (const float4*)wrow;
    float4 q0 = wv[0], q1 = wv[1], q2 = wv[2], q3 = wv[3];
    float p[16] = {q0.x,q0.y,q0.z,q0.w, q1.x,q1.y,q1.z,q1.w,
                   q2.x,q2.y,q2.z,q2.w, q3.x,q3.y,q3.z,q3.w};
    float mx = p[0];
    #pragma unroll
    for (int k = 1; k < 16; k++) mx = fmaxf(mx, p[k]);
    float s = 0.f;
    #pragma unroll
    for (int k = 0; k < 16; k++) { p[k] = __expf(p[k] - mx); s += p[k]; }
    float inv = 1.f / s;
    #pragma unroll
    for (int k = 0; k < 16; k++) p[k] *= inv;

    float c0  = p[8]+p[9]+p[10]+p[11]+p[12]+p[13]+p[14]+p[15];
    float ca  = p[2]+p[3]+p[6]+p[7]-p[8]-p[9]-p[12]-p[13];
    float cb  = p[4]+p[5]+p[6]+p[7]-p[8]-p[9]-p[10]-p[11];
    float cab = p[1]-p[2]-p[4]-2.f*p[6]-p[7]+p[8]+2.f*p[9]+p[11]+p[13]-p[14];
    coef[t] = make_float4(c0, ca, cb, cab);
}

// ---------------------------------------------------------------------------
// Batch-major conv(logic-tree)+orpool.  in: [CIN*HIN*HIN][128], out:
// [F*HP*HP][128].  Thread = (record, b); o/record is wave-uniform -> all
// metadata loads broadcast; activation gathers coalesced across b.
// Patch index tt: c = tt/(KS*KS), r = tt%(KS*KS), y = oh + r/KS - PAD, ...
// ---------------------------------------------------------------------------
template <int CIN, int KS, int PAD, int HIN, int F>
__global__ __launch_bounds__(256) void conv_bm(
    const float* __restrict__ in,
    const int* __restrict__ idx0,   // [2, F, 4]
    const int* __restrict__ idx1,   // [2, F, 2]
    const int* __restrict__ idx2,   // [2, F, 1]
    const float4* __restrict__ cf0,
    const float4* __restrict__ cf1,
    const float4* __restrict__ cf2,
    float* __restrict__ out)
{
    constexpr int HP = (HIN + 2 * PAD - KS + 1) / 2;
    constexpr int NREC = F * HP * HP;
    int t = blockIdx.x * 256 + threadIdx.x;
    if (t >= NREC * 128) return;
    int b   = t & 127;
    int rec = t >> 7;
    int pw = rec % HP;
    int ph = (rec / HP) % HP;
    int f  = rec / (HP * HP);

    int a0[4], b0[4];
    #pragma unroll
    for (int g = 0; g < 4; g++) { a0[g] = idx0[f*4+g]; b0[g] = idx0[F*4 + f*4+g]; }
    int a1[2], b1[2];
    #pragma unroll
    for (int g = 0; g < 2; g++) { a1[g] = idx1[f*2+g]; b1[g] = idx1[F*2 + f*2+g]; }
    int a2 = idx2[f], b2 = idx2[F + f];
    float4 C0[4] = {cf0[f*4], cf0[f*4+1], cf0[f*4+2], cf0[f*4+3]};
    float4 C1[2] = {cf1[f*2], cf1[f*2+1]};
    float4 C2 = cf2[f];

    float m = -1e30f;
    #pragma unroll
    for (int dy = 0; dy < 2; dy++) {
        #pragma unroll
        for (int dx = 0; dx < 2; dx++) {
            int oh = 2 * ph + dy, ow = 2 * pw + dx;
            float h0[4];
            #pragma unroll
            for (int g = 0; g < 4; g++) {
                float va, vb;
                {
                    int tt = a0[g];
                    int c = tt / (KS * KS), r = tt % (KS * KS);
                    int y = oh + r / KS - PAD, x = ow + r % KS - PAD;
                    bool ok = (PAD == 0) || (y >= 0 && y < HIN && x >= 0 && x < HIN);
                    va = ok ? in[((c * HIN + y) * HIN + x) * 128 + b] : 0.f;
                }
                {
                    int tt = b0[g];
                    int c = tt / (KS * KS), r = tt % (KS * KS);
                    int y = oh + r / KS - PAD, x = ow + r % KS - PAD;
                    bool ok = (PAD == 0) || (y >= 0 && y < HIN && x >= 0 && x < HIN);
                    vb = ok ? in[((c * HIN + y) * HIN + x) * 128 + b] : 0.f;
                }
                h0[g] = gev(C0[g], va, vb);
            }
            float h1[2];
            #pragma unroll
            for (int g = 0; g < 2; g++)
                h1[g] = gev(C1[g], sel4(h0, a1[g]), sel4(h0, b1[g]));
            float v = gev(C2, sel2(h1, a2), sel2(h1, b2));
            m = fmaxf(m, v);
        }
    }
    out[rec * 128 + b] = m;
}

// ---------------------------------------------------------------------------
// Batch-major FC logic layer: out[o][b] = gate(h[i0[o]][b], h[i1[o]][b]).
// Grid sized exactly (Dout*128 % 256 == 0 for all three layers).
// ---------------------------------------------------------------------------
__global__ __launch_bounds__(256) void fc_bm(
    const float* __restrict__ h, const int* __restrict__ idx, int Dout,
    const float4* __restrict__ cf, float* __restrict__ out)
{
    int t = blockIdx.x * 256 + threadIdx.x;
    int b = t & 127, o = t >> 7;
    float4 c = cf[o];
    int ia = idx[o], ib = idx[Dout + o];
    out[o * 128 + b] = gev(c, h[ia * 128 + b], h[ib * 128 + b]);
}

// ---------------------------------------------------------------------------
// GroupSum from f3 [5120][128]: out[b][g] = sum_{s<512} f3[g*512+s][b] / 30.
// ---------------------------------------------------------------------------
__global__ __launch_bounds__(256) void gsum_bm(
    const float* __restrict__ f3, float* __restrict__ out)
{
    int t = blockIdx.x * 256 + threadIdx.x;   // 1280 threads
    if (t >= 1280) return;
    int b = t & 127, g = t >> 7;
    if (b >= 100) return;
    const float* p = f3 + g * 512 * 128 + b;
    float s0 = 0.f, s1 = 0.f, s2 = 0.f, s3 = 0.f;
    #pragma unroll 4
    for (int i = 0; i < 512; i += 4) {
        s0 += p[(i + 0) * 128];
        s1 += p[(i + 1) * 128];
        s2 += p[(i + 2) * 128];
        s3 += p[(i + 3) * 128];
    }
    out[b * 10 + g] = (s0 + s1 + s2 + s3) * (1.f / 30.f);
}

extern "C" void kernel_launch(void* const* d_in, const int* in_sizes, int n_in,
                              void* d_out, int out_size, void* d_ws, size_t ws_size,
                              hipStream_t stream)
{
    const float* x     = (const float*)d_in[0];
    const int*   c1i0  = (const int*)d_in[1];  const float* c1w0 = (const float*)d_in[2];
    const int*   c1i1  = (const int*)d_in[3];  const float* c1w1 = (const float*)d_in[4];
    const int*   c1i2  = (const int*)d_in[5];  const float* c1w2 = (const float*)d_in[6];
    const int*   c2i0  = (const int*)d_in[7];  const float* c2w0 = (const float*)d_in[8];
    const int*   c2i1  = (const int*)d_in[9];  const float* c2w1 = (const float*)d_in[10];
    const int*   c2i2  = (const int*)d_in[11]; const float* c2w2 = (const float*)d_in[12];
    const int*   c3i0  = (const int*)d_in[13]; const float* c3w0 = (const float*)d_in[14];
    const int*   c3i1  = (const int*)d_in[15]; const float* c3w1 = (const float*)d_in[16];
    const int*   c3i2  = (const int*)d_in[17]; const float* c3w2 = (const float*)d_in[18];
    const int*   fc1i  = (const int*)d_in[19]; const float* fc1w = (const float*)d_in[20];
    const int*   fc2i  = (const int*)d_in[21]; const float* fc2w = (const float*)d_in[22];
    const int*   fc3i  = (const int*)d_in[23]; const float* fc3w = (const float*)d_in[24];

    // ws layout (bytes, all 16B-aligned):
    //   coef  @ 0         : 37296 * 16 = 596736
    //   xb    @ 596736    : 784   * 128 * 4 = 401408   [pix][b]
    //   p1    @ 998144    : 2304  * 128 * 4 = 1179648  [16*12*12][b]
    //   p2    @ 2177792   : 1728  * 128 * 4 = 884736   [48*6*6][b]
    //   p3    @ 3062528   : 1296  * 128 * 4 = 663552   [144*3*3][b]
    //   f1    @ 3726080   : 20480 * 128 * 4 = 10485760
    //   f2    @ 14211840  : 10240 * 128 * 4 = 5242880
    //   f3    @ 19454720  : 5120  * 128 * 4 = 2621440   (end 22076160)
    char* ws = (char*)d_ws;
    float4* coef = (float4*)ws;
    float* xb = (float*)(ws + 596736);
    float* p1 = (float*)(ws + 998144);
    float* p2 = (float*)(ws + 2177792);
    float* p3 = (float*)(ws + 3062528);
    float* f1 = (float*)(ws + 3726080);
    float* f2 = (float*)(ws + 14211840);
    float* f3 = (float*)(ws + 19454720);

    // coef (146 blocks) + binarize/transpose (392 blocks)
    setup_kernel<<<538, 256, 0, stream>>>(
        c1w0, c1w1, c1w2, c2w0, c2w1, c2w2, c3w0, c3w1, c3w2,
        fc1w, fc2w, fc3w, x, coef, xb);

    // c1: xb[784][128] -> p1[2304][128]   (conv5 pad0 28->24, pool ->12)
    conv_bm<1, 5, 0, 28, 16><<<1152, 256, 0, stream>>>(
        xb, c1i0, c1i1, c1i2, coef + 0, coef + 64, coef + 96, p1);

    // c2: p1 -> p2[1728][128]   (conv3 pad1 12->12, pool ->6)
    conv_bm<16, 3, 1, 12, 48><<<864, 256, 0, stream>>>(
        p1, c2i0, c2i1, c2i2, coef + 112, coef + 304, coef + 400, p2);

    // c3: p2 -> p3[1296][128]   (conv3 pad1 6->6, pool ->3)
    conv_bm<48, 3, 1, 6, 144><<<648, 256, 0, stream>>>(
        p2, c3i0, c3i1, c3i2, coef + 448, coef + 1024, coef + 1312, p3);

    fc_bm<<<10240, 256, 0, stream>>>(p3, fc1i, 20480, coef + 1456, f1);
    fc_bm<<<5120,  256, 0, stream>>>(f1, fc2i, 10240, coef + 21936, f2);
    fc_bm<<<2560,  256, 0, stream>>>(f2, fc3i, 5120,  coef + 32176, f3);

    gsum_bm<<<5, 256, 0, stream>>>(f3, (float*)d_out);
}